// Round 8
// baseline (4620.560 us; speedup 1.0000x reference)
//
#include <hip/hip_runtime.h>
#include <hip/hip_bf16.h>

#define BDIM 4
#define VDIM 20000
#define DDIM 64
#define RDIM 64
#define EDIM 200000
#define BV (BDIM*VDIM)
#define LN_EPS 1e-5f

typedef __hip_bfloat16 bf16;

__device__ __forceinline__ float ldf(const float* p, size_t i){ return p[i]; }
__device__ __forceinline__ float ldf(const bf16* p, size_t i){ return __bfloat162float(p[i]); }
__device__ __forceinline__ void stf(float* p, size_t i, float v){ p[i] = v; }
__device__ __forceinline__ void stf(bf16* p, size_t i, float v){ p[i] = __float2bfloat16(v); }

// ---- diagnostic fill: absmax becomes a readout channel ----
__global__ void fill_kernel(float* __restrict__ out, float v, int n){
  int t = blockIdx.x * 256 + threadIdx.x;
  if (t < n) out[t] = v;
}

// ---- normalize integer inputs: detect int64-vs-int32 on device ----
__global__ void prep_idx_kernel(const int* __restrict__ ei_raw, const int* __restrict__ hi_raw,
                                int* __restrict__ ei, int* __restrict__ hi){
  __shared__ int s64;
  if (threadIdx.x == 0){
    int z = 1;
    for (int j = 1; j < 1024; j += 2) if (ei_raw[j] != 0){ z = 0; break; }
    s64 = z;
  }
  __syncthreads();
  int is64 = s64;
  int t = blockIdx.x * 256 + threadIdx.x;
  if (t < 3*EDIM) ei[t] = is64 ? ei_raw[2*t] : ei_raw[t];
  if (t < BDIM)   hi[t] = is64 ? hi_raw[2*t] : hi_raw[t];
}

// ---- z projections: qk_z (B*4096) and zr[2] (each B*4096) ----
__global__ void zcalc_kernel(const float* __restrict__ z,
                             const float* __restrict__ qkzw, const float* __restrict__ qkzb,
                             const float* __restrict__ vfw,  const float* __restrict__ vfb,
                             float* __restrict__ qk_z, float* __restrict__ zr){
  int idx = blockIdx.x * 256 + threadIdx.x;
  if (idx >= 49152) return;
  int which = idx >> 14;
  int r = idx & 16383;
  int b = r >> 12;
  int j = r & 4095;
  const float* wrow; float bias; float* outp;
  if (which == 0){ wrow = qkzw + (size_t)j*DDIM; bias = qkzb[j]; outp = qk_z; }
  else { int i = which - 1; wrow = vfw + (size_t)(i*4096 + j)*DDIM; bias = vfb[i*4096 + j]; outp = zr + i*16384; }
  const float* zrow = z + (size_t)b*DDIM;
  float acc = bias;
  for (int d = 0; d < DDIM; d++) acc += zrow[d] * wrow[d];
  outp[r] = acc;
}

// ---- hidden of init-qk MLP ----
__global__ void hid_qk_kernel(const float* __restrict__ x, const float* __restrict__ noise,
                              const float* __restrict__ w1, const float* __restrict__ b1,
                              bf16* __restrict__ H){
  int t = blockIdx.x * 256 + threadIdx.x;
  if (t >= BV*64) return;
  int row = t >> 6, i = t & 63;
  const float* wr = w1 + (size_t)i*65;
  const float* xr = x + (size_t)row*64;
  float a = b1[i] + wr[64] * noise[row];
  for (int j = 0; j < 64; j++) a += wr[j] * xr[j];
  H[t] = __float2bfloat16(fmaxf(a, 0.f));
}

// ---- hidden of init-v MLP: concat(x, onehot(h_index)) ----
__global__ void hid_v_kernel(const float* __restrict__ x, const int* __restrict__ h_index,
                             const float* __restrict__ w1, const float* __restrict__ b1,
                             bf16* __restrict__ H){
  int t = blockIdx.x * 256 + threadIdx.x;
  if (t >= BV*64) return;
  int row = t >> 6, i = t & 63;
  int b = row / VDIM, v = row - b*VDIM;
  const float* wr = w1 + (size_t)i*128;
  const float* xr = x + (size_t)row*64;
  float a = b1[i];
  if (v == h_index[b]){ for (int j = 0; j < 64; j++) a += wr[64+j]; }
  for (int j = 0; j < 64; j++) a += wr[j] * xr[j];
  H[t] = __float2bfloat16(fmaxf(a, 0.f));
}

// ---- generic hidden: H = relu(in @ w1^T + b1) ----
template<typename T>
__global__ void hid64_kernel(const T* __restrict__ in, const float* __restrict__ w1,
                             const float* __restrict__ b1, bf16* __restrict__ H){
  int t = blockIdx.x * 256 + threadIdx.x;
  if (t >= BV*64) return;
  int row = t >> 6, i = t & 63;
  const float* wr = w1 + (size_t)i*64;
  size_t rb = (size_t)row*64;
  float a = b1[i];
  for (int j = 0; j < 64; j++) a += ldf(in, rb + j) * wr[j];
  H[t] = __float2bfloat16(fmaxf(a, 0.f));
}

// ---- second MLP layer: out = H @ w2^T + b2 ----
template<typename T>
__global__ void mlp_out_kernel(const bf16* __restrict__ H, const float* __restrict__ w2,
                               const float* __restrict__ b2, T* __restrict__ out){
  int t = blockIdx.x * 256 + threadIdx.x;
  if (t >= BV*64) return;
  int row = t >> 6, i = t & 63;
  const float* wr = w2 + (size_t)i*64;
  const bf16* hr = H + (size_t)row*64;
  float a = b2[i];
  for (int j = 0; j < 64; j++) a += __bfloat162float(hr[j]) * wr[j];
  stf(out, (size_t)t, a);
}

// ---- rspmm: atomic scatter per edge; guards malformed edges ----
template<typename T>
__global__ void rspmm_kernel(const int* __restrict__ ei, const float* __restrict__ zrel,
                             const T* __restrict__ X, float* __restrict__ C){
  int e = blockIdx.x;
  int c = threadIdx.x;
  int bb = c >> 6, dd = c & 63;
  int dst = ei[e*3], rel = ei[e*3+1], src = ei[e*3+2];
  if ((unsigned)dst >= VDIM || (unsigned)rel >= RDIM || (unsigned)src >= VDIM) return;
  float m = zrel[bb*4096 + rel*64 + dd] * ldf(X, ((size_t)bb*VDIM + src)*64 + dd);
  atomicAdd(&C[((size_t)bb*VDIM + dst)*64 + dd], m);
}

// ---- C += alpha[f] * X ----
template<typename T>
__global__ void axpy_kernel(float* __restrict__ C, const T* __restrict__ X,
                            const float* __restrict__ alpha){
  int t = blockIdx.x * 256 + threadIdx.x;
  if (t >= BV*64) return;
  int f = t & 63;
  C[t] += alpha[f] * ldf(X, (size_t)t);
}

// ---- X = LN(Y)*g + b + X ----
template<typename T>
__global__ void ln_res_kernel(const float* __restrict__ Y, T* __restrict__ X,
                              const float* __restrict__ g, const float* __restrict__ bb2){
  int row = blockIdx.x * 256 + threadIdx.x;
  if (row >= BV) return;
  const float* yr = Y + (size_t)row*64;
  float mu = 0.f;
  for (int f = 0; f < 64; f++) mu += yr[f];
  mu *= (1.f/64.f);
  float var = 0.f;
  for (int f = 0; f < 64; f++){ float c = yr[f] - mu; var += c*c; }
  var *= (1.f/64.f);
  float rs = rsqrtf(var + LN_EPS);
  size_t rb = (size_t)row*64;
  for (int f = 0; f < 64; f++){
    float v = (yr[f] - mu) * rs * g[f] + bb2[f] + ldf(X, rb + f);
    stf(X, rb + f, v);
  }
}

// ---- O = LN(Y)*g + b ----
template<typename Ti, typename To>
__global__ void ln_kernel(const Ti* __restrict__ Y, To* __restrict__ O,
                          const float* __restrict__ g, const float* __restrict__ bb2){
  int row = blockIdx.x * 256 + threadIdx.x;
  if (row >= BV) return;
  size_t rb = (size_t)row*64;
  float mu = 0.f;
  for (int f = 0; f < 64; f++) mu += ldf(Y, rb + f);
  mu *= (1.f/64.f);
  float var = 0.f;
  for (int f = 0; f < 64; f++){ float c = ldf(Y, rb + f) - mu; var += c*c; }
  var *= (1.f/64.f);
  float rs = rsqrtf(var + LN_EPS);
  for (int f = 0; f < 64; f++)
    stf(O, rb + f, (ldf(Y, rb + f) - mu) * rs * g[f] + bb2[f]);
}

// ---- qk projection: Q fp32, K bf16 ----
template<typename T>
__global__ void qkproj_kernel(const T* __restrict__ A, const float* __restrict__ w,
                              const float* __restrict__ bias,
                              float* __restrict__ Q, bf16* __restrict__ K){
  int t = blockIdx.x * 256 + threadIdx.x;
  if (t >= BV*128) return;
  int row = t >> 7, j = t & 127;
  const float* wr = w + (size_t)j*64;
  size_t rb = (size_t)row*64;
  float a = bias[j];
  for (int i = 0; i < 64; i++) a += ldf(A, rb + i) * wr[i];
  if (j < 64) Q[rb + j] = a;
  else        K[rb + (j - 64)] = __float2bfloat16(a);
}

// ---- per-head L2 normalize ----
__global__ void qknorm_kernel(float* __restrict__ Q, bf16* __restrict__ K){
  int t = blockIdx.x * 256 + threadIdx.x;
  if (t >= BV*8) return;
  int row = t >> 3, r = t & 7;
  int h = r & 3; bool isk = (r >= 4);
  size_t base = (size_t)row*64 + h*16;
  if (!isk){
    float s = 0.f;
    for (int i = 0; i < 16; i++){ float v = Q[base+i]; s += v*v; }
    float sc = 1.f / fmaxf(sqrtf(s), 1e-12f);
    for (int i = 0; i < 16; i++) Q[base+i] *= sc;
  } else {
    float s = 0.f;
    for (int i = 0; i < 16; i++){ float v = __bfloat162float(K[base+i]); s += v*v; }
    float sc = 1.f / fmaxf(sqrtf(s), 1e-12f);
    for (int i = 0; i < 16; i++) K[base+i] = __float2bfloat16(__bfloat162float(K[base+i]) * sc);
  }
}

// ---- kvs / ksum / vsum ----
template<typename T>
__global__ void kvs_kernel(const bf16* __restrict__ K, const T* __restrict__ Xv,
                           float* __restrict__ kvs){
  int t = blockIdx.x * 256 + threadIdx.x;
  if (t >= 4*4*16*16*64) return;
  int ch = t & 63; int rest = t >> 6;
  int Dp = rest & 15; rest >>= 4;
  int d  = rest & 15; rest >>= 4;
  int h  = rest & 3;  int b = rest >> 2;
  int v0 = ch * 313, v1 = v0 + 313; if (v1 > VDIM) v1 = VDIM;
  float s = 0.f;
  for (int v = v0; v < v1; v++){
    size_t rb = ((size_t)b*VDIM + v)*64 + h*16;
    s += __bfloat162float(K[rb + d]) * ldf(Xv, rb + Dp);
  }
  atomicAdd(&kvs[b*1024 + (h*16 + d)*16 + Dp], s);
}

__global__ void ksum_kernel(const bf16* __restrict__ K, float* __restrict__ ksum){
  int t = blockIdx.x * 256 + threadIdx.x;
  if (t >= 4*4*16*64) return;
  int ch = t & 63; int rest = t >> 6;
  int d = rest & 15; rest >>= 4;
  int h = rest & 3;  int b = rest >> 2;
  int v0 = ch * 313, v1 = v0 + 313; if (v1 > VDIM) v1 = VDIM;
  float s = 0.f;
  for (int v = v0; v < v1; v++)
    s += __bfloat162float(K[((size_t)b*VDIM + v)*64 + h*16 + d]);
  atomicAdd(&ksum[b*64 + h*16 + d], s);
}

template<typename T>
__global__ void vsum_kernel(const T* __restrict__ Xv, float* __restrict__ vsum){
  int t = blockIdx.x * 256 + threadIdx.x;
  if (t >= 4*64*64) return;
  int ch = t & 63; int rest = t >> 6;
  int f = rest & 63; int b = rest >> 6;
  int v0 = ch * 313, v1 = v0 + 313; if (v1 > VDIM) v1 = VDIM;
  float s = 0.f;
  for (int v = v0; v < v1; v++)
    s += ldf(Xv, ((size_t)b*VDIM + v)*64 + f);
  atomicAdd(&vsum[b*64 + f], s);
}

// ---- attention output: A = x + num/den ----
template<typename T>
__global__ void attn_out_kernel(const float* __restrict__ x, const float* __restrict__ Q,
                                const T* __restrict__ Xv, const float* __restrict__ kvs,
                                const float* __restrict__ ksum, const float* __restrict__ vsum,
                                T* __restrict__ A){
  int t = blockIdx.x * 256 + threadIdx.x;
  if (t >= BV*64) return;
  int row = t >> 6, f = t & 63;
  int b = row / VDIM;
  int h = f >> 4, dl = f & 15;
  size_t rb = (size_t)row*64;
  float vv = ldf(Xv, rb + f);
  float num = vsum[b*64 + f] + vv * (float)VDIM;
  float den = 2.0f * (float)VDIM;
  for (int j = 0; j < 16; j++){
    float qj = Q[rb + h*16 + j];
    num += qj * kvs[b*1024 + (h*16 + j)*16 + dl];
    den += qj * ksum[b*64 + h*16 + j];
  }
  stf(A, (size_t)t, x[t] + num / den);
}

// ---- final: out(fp32) = LN(X1 + Y2)*g + b ----
template<typename T>
__global__ void final_ln_kernel(const T* __restrict__ X1, const float* __restrict__ Y2,
                                const float* __restrict__ g, const float* __restrict__ bb2,
                                float* __restrict__ out){
  int row = blockIdx.x * 256 + threadIdx.x;
  if (row >= BV) return;
  size_t rb = (size_t)row*64;
  float mu = 0.f;
  for (int f = 0; f < 64; f++) mu += ldf(X1, rb+f) + Y2[rb+f];
  mu *= (1.f/64.f);
  float var = 0.f;
  for (int f = 0; f < 64; f++){ float c = ldf(X1, rb+f) + Y2[rb+f] - mu; var += c*c; }
  var *= (1.f/64.f);
  float rs = rsqrtf(var + LN_EPS);
  for (int f = 0; f < 64; f++){
    float c = ldf(X1, rb+f) + Y2[rb+f] - mu;
    out[rb + f] = c * rs * g[f] + bb2[f];
  }
}

// ================= host side =================
static const int DICT_SIZES[42] = {
  5120000,256,256,80000,262144,4096,4160,64,4096,64,
  8192,64,4096,64,8192,128,8192,128,8192,128,
  128,128,128,524288,8192,8192,128,8192,128,128,
  128,128,4096,64,4096,64,64,64,64,64,
  4,600000};

template<typename T>
static void run_pipeline(const float* const* N, const int* ei, const int* hi,
                         float* qk_z, float* zr, float* kvs, float* C,
                         T* A, T* B, float* outp, hipStream_t stream){
  float* ksum = kvs + 4096;
  float* vsum = kvs + 4352;
  bf16* D = (bf16*)outp;           // d_out memory as bf16 scratch; overwritten by final_ln

  const int GE = BV*64/256;
  const int GR = (BV+255)/256;

  zcalc_kernel<<<192, 256, 0, stream>>>(N[1], N[4], N[5], N[23], N[24], qk_z, zr);

  // ---- qk stream ----
  hid_qk_kernel<<<GE, 256, 0, stream>>>(N[0], N[3], N[6], N[7], D);
  mlp_out_kernel<T><<<GE, 256, 0, stream>>>(D, N[8], N[9], A);
  for (int i = 0; i < 2; i++){
    hipMemsetAsync(C, 0, (size_t)BV*64*4, stream);
    rspmm_kernel<T><<<EDIM, 256, 0, stream>>>(ei, qk_z, A, C);
    axpy_kernel<T><<<GE, 256, 0, stream>>>(C, A, N[20] + i*64);
    hid64_kernel<float><<<GE, 256, 0, stream>>>(C, N[16] + i*4096, N[17] + i*64, D);
    mlp_out_kernel<float><<<GE, 256, 0, stream>>>(D, N[18] + i*4096, N[19] + i*64, C);
    ln_res_kernel<T><<<GR, 256, 0, stream>>>(C, A, N[21] + i*64, N[22] + i*64);
  }
  // ---- v stream ----
  hid_v_kernel<<<GE, 256, 0, stream>>>(N[0], hi, N[10], N[11], D);
  mlp_out_kernel<T><<<GE, 256, 0, stream>>>(D, N[12], N[13], B);
  for (int i = 0; i < 2; i++){
    hipMemsetAsync(C, 0, (size_t)BV*64*4, stream);
    rspmm_kernel<T><<<EDIM, 256, 0, stream>>>(ei, zr + i*16384, B, C);
    axpy_kernel<T><<<GE, 256, 0, stream>>>(C, B, N[29] + i*64);
    hid64_kernel<float><<<GE, 256, 0, stream>>>(C, N[25] + i*4096, N[26] + i*64, D);
    mlp_out_kernel<float><<<GE, 256, 0, stream>>>(D, N[27] + i*4096, N[28] + i*64, C);
    ln_res_kernel<T><<<GR, 256, 0, stream>>>(C, B, N[30] + i*64, N[31] + i*64);
  }
  // ---- attention ----
  qkproj_kernel<T><<<BV*128/256, 256, 0, stream>>>(A, N[14], N[15], C, D);
  qknorm_kernel<<<(BV*8+255)/256, 256, 0, stream>>>(C, D);
  hipMemsetAsync(kvs, 0, 4608u*4, stream);
  kvs_kernel<T><<<(4*4*16*16*64)/256, 256, 0, stream>>>(D, B, kvs);
  ksum_kernel<<<(4*4*16*64)/256, 256, 0, stream>>>(D, ksum);
  vsum_kernel<T><<<(4*64*64)/256, 256, 0, stream>>>(B, vsum);
  attn_out_kernel<T><<<GE, 256, 0, stream>>>(N[0], C, B, kvs, ksum, vsum, A);
  ln_kernel<T, T><<<GR, 256, 0, stream>>>(A, B, N[36], N[37]);
  // ---- final FFN + LN ----
  hid64_kernel<T><<<GE, 256, 0, stream>>>(B, N[32], N[33], D);
  mlp_out_kernel<float><<<GE, 256, 0, stream>>>(D, N[34], N[35], C);
  final_ln_kernel<T><<<GR, 256, 0, stream>>>(B, C, N[38], N[39], outp);
}

extern "C" void kernel_launch(void* const* d_in, const int* in_sizes, int n_in,
                              void* d_out, int out_size, void* d_ws, size_t ws_size,
                              hipStream_t stream){
  float* outp = (float*)d_out;
  const int GOUT = (out_size + 255) / 256;

  if (n_in != 42){
    fill_kernel<<<GOUT, 256, 0, stream>>>(outp, 2000.0f + (float)n_in, out_size);
    return;
  }
  auto sz_ok = [&](int s, int e)->bool{
    if (s == e) return true;
    if ((e == 4 || e == 600000) && s == 2*e) return true;   // int64 double-count
    return false;
  };
  int bad = -1;
  for (int i = 0; i < 42 && bad < 0; i++)
    if (!sz_ok(in_sizes[i], DICT_SIZES[i])) bad = i;
  if (bad >= 0){
    fill_kernel<<<GOUT, 256, 0, stream>>>(outp, 1000.0f + (float)bad, out_size);
    return;
  }

  const float* N[40];
  for (int i = 0; i < 40; i++) N[i] = (const float*)d_in[i];
  const int* hi_raw = (const int*)d_in[40];
  const int* ei_raw = (const int*)d_in[41];

  // ---- workspace layout ----
  char* p = (char*)d_ws;
  auto alloc = [&](size_t bytes)->char*{ char* r = p; p += (bytes + 255) / 256 * 256; return r; };
  int* ei     = (int*)alloc((size_t)3*EDIM*4);
  int* hi     = (int*)alloc(256);
  float* qk_z = (float*)alloc(16384u*4);
  float* zr   = (float*)alloc(32768u*4);
  float* kvs  = (float*)alloc(4608u*4);
  float* C    = (float*)alloc((size_t)BV*64*4);
  size_t fixed = (size_t)(p - (char*)d_ws);
  bool f32ok = ws_size >= fixed + 2*(size_t)BV*64*4 + 1024;

  prep_idx_kernel<<<(3*EDIM+255)/256, 256, 0, stream>>>(ei_raw, hi_raw, ei, hi);

  if (f32ok){
    float* A = (float*)alloc((size_t)BV*64*4);
    float* B = (float*)alloc((size_t)BV*64*4);
    run_pipeline<float>(N, ei, hi, qk_z, zr, kvs, C, A, B, outp, stream);
  } else {
    bf16* A = (bf16*)alloc((size_t)BV*64*2);
    bf16* B = (bf16*)alloc((size_t)BV*64*2);
    run_pipeline<bf16>(N, ei, hi, qk_z, zr, kvs, C, A, B, outp, stream);
  }
}

// Round 9
// 1820.015 us; speedup vs baseline: 2.5387x; 2.5387x over previous
//
#include <hip/hip_runtime.h>
#include <hip/hip_bf16.h>

#define BDIM 4
#define VDIM 20000
#define DDIM 64
#define RDIM 64
#define EDIM 200000
#define BV (BDIM*VDIM)
#define LN_EPS 1e-5f

typedef __hip_bfloat16 bf16;

__device__ __forceinline__ float ldf(const float* p, size_t i){ return p[i]; }
__device__ __forceinline__ float ldf(const bf16* p, size_t i){ return __bfloat162float(p[i]); }
__device__ __forceinline__ void stf(float* p, size_t i, float v){ p[i] = v; }
__device__ __forceinline__ void stf(bf16* p, size_t i, float v){ p[i] = __float2bfloat16(v); }

__device__ __forceinline__ float wave_sum64(float x){
  #pragma unroll
  for (int o = 32; o > 0; o >>= 1) x += __shfl_xor(x, o, 64);
  return x;
}
__device__ __forceinline__ float head_sum16(float x){
  #pragma unroll
  for (int o = 8; o > 0; o >>= 1) x += __shfl_xor(x, o, 64);
  return x;
}

// ---- diagnostic fill ----
__global__ void fill_kernel(float* __restrict__ out, float v, int n){
  int t = blockIdx.x * 256 + threadIdx.x;
  if (t < n) out[t] = v;
}

// ---- normalize integer inputs: detect int64-vs-int32 on device ----
__global__ void prep_idx_kernel(const int* __restrict__ ei_raw, const int* __restrict__ hi_raw,
                                int* __restrict__ ei, int* __restrict__ hi){
  __shared__ int s64;
  if (threadIdx.x == 0){
    int z = 1;
    for (int j = 1; j < 1024; j += 2) if (ei_raw[j] != 0){ z = 0; break; }
    s64 = z;
  }
  __syncthreads();
  int is64 = s64;
  int t = blockIdx.x * 256 + threadIdx.x;
  if (t < 3*EDIM) ei[t] = is64 ? ei_raw[2*t] : ei_raw[t];
  if (t < BDIM)   hi[t] = is64 ? hi_raw[2*t] : hi_raw[t];
}

// ---- zero counts + kvs ----
__global__ void zero_kernel(int* __restrict__ counts, float* __restrict__ fbuf){
  int i = blockIdx.x * 256 + threadIdx.x;
  if (i < VDIM + 1) counts[i] = 0;
  if (i < 4608) fbuf[i] = 0.f;
}

// ---- counting sort by destination -> CSR ----
__global__ void count_kernel(const int* __restrict__ ei, int* __restrict__ counts){
  int e = blockIdx.x * 256 + threadIdx.x;
  if (e < EDIM){
    int dst = ei[e*3], rel = ei[e*3+1], src = ei[e*3+2];
    if ((unsigned)dst < VDIM && (unsigned)rel < RDIM && (unsigned)src < VDIM)
      atomicAdd(&counts[dst], 1);
  }
}

__global__ void scan_kernel(const int* __restrict__ counts, int* __restrict__ row_ptr, int* __restrict__ cursor){
  __shared__ int buf[256];
  int tid = threadIdx.x;
  int base = 0;
  for (int c0 = 0; c0 < VDIM; c0 += 256){
    int idx = c0 + tid;
    int val = (idx < VDIM) ? counts[idx] : 0;
    buf[tid] = val;
    __syncthreads();
    for (int off = 1; off < 256; off <<= 1){
      int t = (tid >= off) ? buf[tid - off] : 0;
      __syncthreads();
      buf[tid] += t;
      __syncthreads();
    }
    int excl = buf[tid] - val;
    if (idx < VDIM){ row_ptr[idx] = base + excl; cursor[idx] = base + excl; }
    base += buf[255];
    __syncthreads();
  }
  if (tid == 0) row_ptr[VDIM] = base;
}

__global__ void scatter_kernel(const int* __restrict__ ei, int* __restrict__ cursor,
                               int* __restrict__ srel, int* __restrict__ ssrc){
  int e = blockIdx.x * 256 + threadIdx.x;
  if (e < EDIM){
    int dst = ei[e*3], rel = ei[e*3+1], src = ei[e*3+2];
    if ((unsigned)dst < VDIM && (unsigned)rel < RDIM && (unsigned)src < VDIM){
      int p = atomicAdd(&cursor[dst], 1);
      srel[p] = rel; ssrc[p] = src;
    }
  }
}

// ---- z projections (verified round-8 semantics) ----
__global__ void zcalc_kernel(const float* __restrict__ z,
                             const float* __restrict__ qkzw, const float* __restrict__ qkzb,
                             const float* __restrict__ vfw,  const float* __restrict__ vfb,
                             float* __restrict__ qk_z, float* __restrict__ zr){
  int idx = blockIdx.x * 256 + threadIdx.x;
  if (idx >= 49152) return;
  int which = idx >> 14;
  int r = idx & 16383;
  int b = r >> 12;
  int j = r & 4095;
  const float* wrow; float bias; float* outp;
  if (which == 0){ wrow = qkzw + (size_t)j*DDIM; bias = qkzb[j]; outp = qk_z; }
  else { int i = which - 1; wrow = vfw + (size_t)(i*4096 + j)*DDIM; bias = vfb[i*4096 + j]; outp = zr + i*16384; }
  const float* zrow = z + (size_t)b*DDIM;
  float acc = bias;
  for (int d = 0; d < DDIM; d++) acc += zrow[d] * wrow[d];
  outp[r] = acc;
}

// ---- rspmm gather: block per destination, no atomics ----
template<typename T>
__global__ __launch_bounds__(256) void rspmm_gather(
    const int* __restrict__ row_ptr, const int* __restrict__ srel,
    const int* __restrict__ ssrc, const float* __restrict__ zrel,
    const T* __restrict__ X, float* __restrict__ out){
  int v = blockIdx.x;
  int b = threadIdx.x >> 6, d = threadIdx.x & 63;
  int s = row_ptr[v], e = row_ptr[v+1];
  const float* zb = zrel + b*RDIM*DDIM + d;
  float acc = 0.f;
  for (int i = s; i < e; i++){
    acc += zb[srel[i]*DDIM] * ldf(X, ((size_t)b*VDIM + ssrc[i])*64 + d);
  }
  out[((size_t)b*VDIM + v)*64 + d] = acc;
}

// ---- init qk_x: fused 2-layer MLP, wave per row ----
template<typename T>
__global__ __launch_bounds__(256) void init_qk_kernel(
    const float* __restrict__ x, const float* __restrict__ noise,
    const float* __restrict__ w1, const float* __restrict__ b1,
    const float* __restrict__ w2, const float* __restrict__ b2,
    T* __restrict__ out){
  __shared__ float w1s[64*66];
  __shared__ float w2s[64*65];
  __shared__ float tb[4*66];
  __shared__ float hb[4*64];
  int tid = threadIdx.x, lane = tid & 63, wid = tid >> 6;
  for (int idx = tid; idx < 64*65; idx += 256){ int d = idx/65, i = idx - d*65; w1s[d*66+i] = w1[idx]; }
  for (int idx = tid; idx < 4096; idx += 256){ int d = idx>>6, i = idx&63; w2s[d*65+i] = w2[idx]; }
  float b1l = b1[lane], b2l = b2[lane];
  __syncthreads();
  for (int r0 = blockIdx.x*4; r0 < BV; r0 += gridDim.x*4){
    int row = r0 + wid;
    size_t rb = (size_t)row*64;
    tb[wid*66+lane] = x[rb+lane];
    if (lane == 0) tb[wid*66+64] = noise[row];
    float h = b1l;
    #pragma unroll
    for (int i = 0; i < 65; i++) h += w1s[lane*66+i] * tb[wid*66+i];
    h = fmaxf(h, 0.f);
    hb[wid*64+lane] = h;
    float y = b2l;
    #pragma unroll
    for (int i = 0; i < 64; i++) y += w2s[lane*65+i] * hb[wid*64+i];
    stf(out, rb+lane, y);
  }
}

// ---- init v_x: fused 2-layer MLP with onehot-block ----
template<typename T>
__global__ __launch_bounds__(256) void init_v_kernel(
    const float* __restrict__ x, const int* __restrict__ h_index,
    const float* __restrict__ w1, const float* __restrict__ b1,
    const float* __restrict__ w2, const float* __restrict__ b2,
    T* __restrict__ out){
  __shared__ float w1s[64*65];
  __shared__ float rs[64];
  __shared__ float w2s[64*65];
  __shared__ float tb[4*64];
  __shared__ float hb[4*64];
  int tid = threadIdx.x, lane = tid & 63, wid = tid >> 6;
  for (int idx = tid; idx < 4096; idx += 256){ int d = idx>>6, i = idx&63; w1s[d*65+i] = w1[d*128+i]; }
  for (int idx = tid; idx < 4096; idx += 256){ int d = idx>>6, i = idx&63; w2s[d*65+i] = w2[idx]; }
  if (tid < 64){ float s = 0.f; for (int i = 0; i < 64; i++) s += w1[tid*128+64+i]; rs[tid] = s; }
  float b1l = b1[lane], b2l = b2[lane];
  int h0 = h_index[0], h1 = h_index[1], h2 = h_index[2], h3 = h_index[3];
  __syncthreads();
  for (int r0 = blockIdx.x*4; r0 < BV; r0 += gridDim.x*4){
    int row = r0 + wid;
    int b = row / VDIM, v = row - b*VDIM;
    int hv = (b == 0) ? h0 : (b == 1) ? h1 : (b == 2) ? h2 : h3;
    size_t rb = (size_t)row*64;
    tb[wid*64+lane] = x[rb+lane];
    float h = b1l + ((v == hv) ? rs[lane] : 0.f);
    #pragma unroll
    for (int i = 0; i < 64; i++) h += w1s[lane*65+i] * tb[wid*64+i];
    h = fmaxf(h, 0.f);
    hb[wid*64+lane] = h;
    float y = b2l;
    #pragma unroll
    for (int i = 0; i < 64; i++) y += w2s[lane*65+i] * hb[wid*64+i];
    stf(out, rb+lane, y);
  }
}

// ---- loop body: X = LN(mlp2(O + alpha*X))*ng + nb + X, fused ----
template<typename T>
__global__ __launch_bounds__(256) void loop_body_kernel(
    const float* __restrict__ O, T* __restrict__ X,
    const float* __restrict__ alpha, const float* __restrict__ w1, const float* __restrict__ b1,
    const float* __restrict__ w2, const float* __restrict__ b2,
    const float* __restrict__ ng, const float* __restrict__ nb){
  __shared__ float w1s[64*65], w2s[64*65], tb[4*64], hb[4*64];
  int tid = threadIdx.x, lane = tid & 63, wid = tid >> 6;
  for (int idx = tid; idx < 4096; idx += 256){
    int d = idx>>6, i = idx&63;
    w1s[d*65+i] = w1[idx]; w2s[d*65+i] = w2[idx];
  }
  float all = alpha[lane], b1l = b1[lane], b2l = b2[lane];
  float ngl = ng[lane], nbl = nb[lane];
  __syncthreads();
  for (int r0 = blockIdx.x*4; r0 < BV; r0 += gridDim.x*4){
    int row = r0 + wid;
    size_t rb = (size_t)row*64;
    float xs = ldf(X, rb+lane);
    tb[wid*64+lane] = O[rb+lane] + all * xs;
    float h = b1l;
    #pragma unroll
    for (int i = 0; i < 64; i++) h += w1s[lane*65+i] * tb[wid*64+i];
    h = fmaxf(h, 0.f);
    hb[wid*64+lane] = h;
    float y = b2l;
    #pragma unroll
    for (int i = 0; i < 64; i++) y += w2s[lane*65+i] * hb[wid*64+i];
    float mu = wave_sum64(y) * (1.f/64.f);
    float c = y - mu;
    float var = wave_sum64(c*c) * (1.f/64.f);
    stf(X, rb+lane, c * rsqrtf(var + LN_EPS) * ngl + nbl + xs);
  }
}

// ---- qk projection + normalize + kvs/ksum/vsum in registers ----
template<typename T>
__global__ __launch_bounds__(256) void qkproj_kernel(
    T* __restrict__ Xqk, const T* __restrict__ Xv,
    const float* __restrict__ w, const float* __restrict__ bias,
    float* __restrict__ kvs, float* __restrict__ ksum, float* __restrict__ vsum){
  __shared__ float ws[128*65];
  __shared__ float tb[4*64];
  int tid = threadIdx.x, lane = tid & 63, wid = tid >> 6;
  for (int idx = tid; idx < 8192; idx += 256){ int r = idx>>6, i = idx&63; ws[r*65+i] = w[idx]; }
  float bq = bias[lane], bk = bias[64+lane];
  int b = blockIdx.x / 250, blk = blockIdx.x % 250;
  float kv[16];
  #pragma unroll
  for (int i = 0; i < 16; i++) kv[i] = 0.f;
  float ks = 0.f, vs = 0.f;
  __syncthreads();
  for (int v0 = blk*4; v0 < VDIM; v0 += 1000){
    int v = v0 + wid;
    size_t row = ((size_t)b*VDIM + v)*64;
    tb[wid*64+lane] = ldf(Xqk, row+lane);
    float q = bq, k = bk;
    #pragma unroll
    for (int i = 0; i < 64; i++){
      float ti = tb[wid*64+i];
      q += ws[lane*65+i] * ti;
      k += ws[(64+lane)*65+i] * ti;
    }
    float qn2 = head_sum16(q*q);
    float kn2 = head_sum16(k*k);
    q = q / fmaxf(sqrtf(qn2), 1e-12f);
    k = k / fmaxf(sqrtf(kn2), 1e-12f);
    float vv = ldf(Xv, row+lane);
    stf(Xqk, row+lane, q);             // qn in place
    ks += k; vs += vv;
    int base = lane & 48;              // h*16
    #pragma unroll
    for (int dl = 0; dl < 16; dl++){
      float vdl = __shfl(vv, base + dl, 64);
      kv[dl] += k * vdl;
    }
  }
  atomicAdd(&ksum[b*64+lane], ks);
  atomicAdd(&vsum[b*64+lane], vs);
  #pragma unroll
  for (int dl = 0; dl < 16; dl++) atomicAdd(&kvs[b*1024 + lane*16 + dl], kv[dl]);
}

// ---- attention finalize + LN: A := LN(x + attn)*g + b (in place over qn) ----
template<typename T>
__global__ __launch_bounds__(256) void attn_final_kernel(
    const float* __restrict__ x, T* __restrict__ A, const T* __restrict__ Xv,
    const float* __restrict__ kvs, const float* __restrict__ ksum, const float* __restrict__ vsum,
    const float* __restrict__ g, const float* __restrict__ bb){
  __shared__ float kvss[4096], kss[256], vss[256];
  int tid = threadIdx.x, lane = tid & 63, wid = tid >> 6;
  for (int i = tid; i < 4096; i += 256) kvss[i] = kvs[i];
  kss[tid] = ksum[tid];
  vss[tid] = vsum[tid];
  float gl = g[lane], bl = bb[lane];
  __syncthreads();
  int h16 = lane & 48, dl = lane & 15;
  for (int r0 = blockIdx.x*4; r0 < BV; r0 += gridDim.x*4){
    int row = r0 + wid;
    int b = row / VDIM;
    size_t rb = (size_t)row*64;
    float qv = ldf(A, rb+lane);
    float vv = ldf(Xv, rb+lane);
    float num = vss[b*64+lane] + vv * (float)VDIM;
    float den = 2.0f * (float)VDIM;
    int kbase = b*1024 + h16*16 + dl;
    int ksbase = b*64 + h16;
    #pragma unroll
    for (int j = 0; j < 16; j++){
      float qj = __shfl(qv, h16 + j, 64);
      num += qj * kvss[kbase + j*16];
      den += qj * kss[ksbase + j];
    }
    float y = x[rb+lane] + num / den;
    float mu = wave_sum64(y) * (1.f/64.f);
    float c = y - mu;
    float var = wave_sum64(c*c) * (1.f/64.f);
    stf(A, rb+lane, c * rsqrtf(var + LN_EPS) * gl + bl);
  }
}

// ---- final: out(fp32) = LN(x1 + mlp2(x1))*g + b, fused ----
template<typename T>
__global__ __launch_bounds__(256) void final_kernel(
    const T* __restrict__ X1,
    const float* __restrict__ w1, const float* __restrict__ b1,
    const float* __restrict__ w2, const float* __restrict__ b2,
    const float* __restrict__ g, const float* __restrict__ bb,
    float* __restrict__ out){
  __shared__ float w1s[64*65], w2s[64*65], tb[4*64], hb[4*64];
  int tid = threadIdx.x, lane = tid & 63, wid = tid >> 6;
  for (int idx = tid; idx < 4096; idx += 256){
    int d = idx>>6, i = idx&63;
    w1s[d*65+i] = w1[idx]; w2s[d*65+i] = w2[idx];
  }
  float b1l = b1[lane], b2l = b2[lane], gl = g[lane], bl = bb[lane];
  __syncthreads();
  for (int r0 = blockIdx.x*4; r0 < BV; r0 += gridDim.x*4){
    int row = r0 + wid;
    size_t rb = (size_t)row*64;
    float xv = ldf(X1, rb+lane);
    tb[wid*64+lane] = xv;
    float h = b1l;
    #pragma unroll
    for (int i = 0; i < 64; i++) h += w1s[lane*65+i] * tb[wid*64+i];
    h = fmaxf(h, 0.f);
    hb[wid*64+lane] = h;
    float y = b2l;
    #pragma unroll
    for (int i = 0; i < 64; i++) y += w2s[lane*65+i] * hb[wid*64+i];
    float t = xv + y;
    float mu = wave_sum64(t) * (1.f/64.f);
    float c = t - mu;
    float var = wave_sum64(c*c) * (1.f/64.f);
    out[rb+lane] = c * rsqrtf(var + LN_EPS) * gl + bl;
  }
}

// ================= host side =================
static const int DICT_SIZES[42] = {
  5120000,256,256,80000,262144,4096,4160,64,4096,64,
  8192,64,4096,64,8192,128,8192,128,8192,128,
  128,128,128,524288,8192,8192,128,8192,128,128,
  128,128,4096,64,4096,64,64,64,64,64,
  4,600000};

template<typename T>
static void run_pipeline(const float* const* N, const int* ei, const int* hi,
                         const int* row_ptr, const int* srel, const int* ssrc,
                         float* qk_z, float* zr, float* kvs, float* Obuf,
                         T* A, T* B, float* outp, hipStream_t stream){
  float* ksum = kvs + 4096;
  float* vsum = kvs + 4352;
  const int GM = 2000;               // wave-per-row kernels: 4 rows/block

  zcalc_kernel<<<192, 256, 0, stream>>>(N[1], N[4], N[5], N[23], N[24], qk_z, zr);

  // ---- qk stream ----
  init_qk_kernel<T><<<GM, 256, 0, stream>>>(N[0], N[3], N[6], N[7], N[8], N[9], A);
  for (int i = 0; i < 2; i++){
    rspmm_gather<T><<<VDIM, 256, 0, stream>>>(row_ptr, srel, ssrc, qk_z, A, Obuf);
    loop_body_kernel<T><<<GM, 256, 0, stream>>>(Obuf, A, N[20] + i*64, N[16] + i*4096, N[17] + i*64,
                                                N[18] + i*4096, N[19] + i*64, N[21] + i*64, N[22] + i*64);
  }
  // ---- v stream ----
  init_v_kernel<T><<<GM, 256, 0, stream>>>(N[0], hi, N[10], N[11], N[12], N[13], B);
  for (int i = 0; i < 2; i++){
    rspmm_gather<T><<<VDIM, 256, 0, stream>>>(row_ptr, srel, ssrc, zr + i*16384, B, Obuf);
    loop_body_kernel<T><<<GM, 256, 0, stream>>>(Obuf, B, N[29] + i*64, N[25] + i*4096, N[26] + i*64,
                                                N[27] + i*4096, N[28] + i*64, N[30] + i*64, N[31] + i*64);
  }
  // ---- attention ----
  qkproj_kernel<T><<<BDIM*250, 256, 0, stream>>>(A, B, N[14], N[15], kvs, ksum, vsum);
  attn_final_kernel<T><<<GM, 256, 0, stream>>>(N[0], A, B, kvs, ksum, vsum, N[36], N[37]);
  // ---- final FFN + LN -> fp32 out ----
  final_kernel<T><<<GM, 256, 0, stream>>>(A, N[32], N[33], N[34], N[35], N[38], N[39], outp);
}

extern "C" void kernel_launch(void* const* d_in, const int* in_sizes, int n_in,
                              void* d_out, int out_size, void* d_ws, size_t ws_size,
                              hipStream_t stream){
  float* outp = (float*)d_out;
  const int GOUT = (out_size + 255) / 256;

  if (n_in != 42){
    fill_kernel<<<GOUT, 256, 0, stream>>>(outp, 2000.0f + (float)n_in, out_size);
    return;
  }
  auto sz_ok = [&](int s, int e)->bool{
    if (s == e) return true;
    if ((e == 4 || e == 600000) && s == 2*e) return true;   // int64 double-count
    return false;
  };
  int bad = -1;
  for (int i = 0; i < 42 && bad < 0; i++)
    if (!sz_ok(in_sizes[i], DICT_SIZES[i])) bad = i;
  if (bad >= 0){
    fill_kernel<<<GOUT, 256, 0, stream>>>(outp, 1000.0f + (float)bad, out_size);
    return;
  }

  const float* N[40];
  for (int i = 0; i < 40; i++) N[i] = (const float*)d_in[i];
  const int* hi_raw = (const int*)d_in[40];
  const int* ei_raw = (const int*)d_in[41];

  // ---- workspace layout ----
  char* p = (char*)d_ws;
  auto alloc = [&](size_t bytes)->char*{ char* r = p; p += (bytes + 255) / 256 * 256; return r; };
  int* ei      = (int*)alloc((size_t)3*EDIM*4);
  int* hi      = (int*)alloc(256);
  int* counts  = (int*)alloc((VDIM+1)*4);
  int* row_ptr = (int*)alloc((VDIM+1)*4);
  int* cursor  = (int*)alloc((VDIM+1)*4);
  int* srel    = (int*)alloc((size_t)EDIM*4);
  int* ssrc    = (int*)alloc((size_t)EDIM*4);
  float* qk_z  = (float*)alloc(16384u*4);
  float* zr    = (float*)alloc(32768u*4);
  float* kvs   = (float*)alloc(4608u*4);
  float* Obuf  = (float*)alloc((size_t)BV*64*4);
  size_t fixed = (size_t)(p - (char*)d_ws);
  bool f32ok = ws_size >= fixed + 2*(size_t)BV*64*4 + 1024;

  // ---- prep: int normalization + CSR sort ----
  prep_idx_kernel<<<(3*EDIM+255)/256, 256, 0, stream>>>(ei_raw, hi_raw, ei, hi);
  zero_kernel<<<(VDIM+256)/256, 256, 0, stream>>>(counts, kvs);
  count_kernel<<<(EDIM+255)/256, 256, 0, stream>>>(ei, counts);
  scan_kernel<<<1, 256, 0, stream>>>(counts, row_ptr, cursor);
  scatter_kernel<<<(EDIM+255)/256, 256, 0, stream>>>(ei, cursor, srel, ssrc);

  if (f32ok){
    float* A = (float*)alloc((size_t)BV*64*4);
    float* B = (float*)alloc((size_t)BV*64*4);
    run_pipeline<float>(N, ei, hi, row_ptr, srel, ssrc, qk_z, zr, kvs, Obuf, A, B, outp, stream);
  } else {
    bf16* A = (bf16*)alloc((size_t)BV*64*2);
    bf16* B = (bf16*)alloc((size_t)BV*64*2);
    run_pipeline<bf16>(N, ei, hi, row_ptr, srel, ssrc, qk_z, zr, kvs, Obuf, A, B, outp, stream);
  }
}

// Round 10
// 1154.142 us; speedup vs baseline: 4.0035x; 1.5769x over previous
//
#include <hip/hip_runtime.h>
#include <hip/hip_bf16.h>

#define BDIM 4
#define VDIM 20000
#define DDIM 64
#define RDIM 64
#define EDIM 200000
#define BV (BDIM*VDIM)
#define LN_EPS 1e-5f
#define NBB 250           // qkproj blocks per batch

typedef __hip_bfloat16 bf16;

__device__ __forceinline__ float ldf(const float* p, size_t i){ return p[i]; }
__device__ __forceinline__ float ldf(const bf16* p, size_t i){ return __bfloat162float(p[i]); }
__device__ __forceinline__ void stf(float* p, size_t i, float v){ p[i] = v; }
__device__ __forceinline__ void stf(bf16* p, size_t i, float v){ p[i] = __float2bfloat16(v); }

__device__ __forceinline__ float wave_sum64(float x){
  #pragma unroll
  for (int o = 32; o > 0; o >>= 1) x += __shfl_xor(x, o, 64);
  return x;
}
__device__ __forceinline__ float head_sum16(float x){
  #pragma unroll
  for (int o = 8; o > 0; o >>= 1) x += __shfl_xor(x, o, 64);
  return x;
}
__device__ __forceinline__ float dot4(float4 a, float4 b){
  return a.x*b.x + a.y*b.y + a.z*b.z + a.w*b.w;
}

// ---- diagnostic fill ----
__global__ void fill_kernel(float* __restrict__ out, float v, int n){
  int t = blockIdx.x * 256 + threadIdx.x;
  if (t < n) out[t] = v;
}

// ---- int width normalize ----
__global__ void prep_idx_kernel(const int* __restrict__ ei_raw, const int* __restrict__ hi_raw,
                                int* __restrict__ ei, int* __restrict__ hi){
  __shared__ int s64;
  if (threadIdx.x == 0){
    int z = 1;
    for (int j = 1; j < 1024; j += 2) if (ei_raw[j] != 0){ z = 0; break; }
    s64 = z;
  }
  __syncthreads();
  int is64 = s64;
  int t = blockIdx.x * 256 + threadIdx.x;
  if (t < 3*EDIM) ei[t] = is64 ? ei_raw[2*t] : ei_raw[t];
  if (t < BDIM)   hi[t] = is64 ? hi_raw[2*t] : hi_raw[t];
}

__global__ void zero_kernel(int* __restrict__ counts){
  int i = blockIdx.x * 256 + threadIdx.x;
  if (i < VDIM + 1) counts[i] = 0;
}

__global__ void count_kernel(const int* __restrict__ ei, int* __restrict__ counts){
  int e = blockIdx.x * 256 + threadIdx.x;
  if (e < EDIM){
    int dst = ei[e*3], rel = ei[e*3+1], src = ei[e*3+2];
    if ((unsigned)dst < VDIM && (unsigned)rel < RDIM && (unsigned)src < VDIM)
      atomicAdd(&counts[dst], 1);
  }
}

__global__ void scan_kernel(const int* __restrict__ counts, int* __restrict__ row_ptr, int* __restrict__ cursor){
  __shared__ int buf[256];
  int tid = threadIdx.x;
  int base = 0;
  for (int c0 = 0; c0 < VDIM; c0 += 256){
    int idx = c0 + tid;
    int val = (idx < VDIM) ? counts[idx] : 0;
    buf[tid] = val;
    __syncthreads();
    for (int off = 1; off < 256; off <<= 1){
      int t = (tid >= off) ? buf[tid - off] : 0;
      __syncthreads();
      buf[tid] += t;
      __syncthreads();
    }
    int excl = buf[tid] - val;
    if (idx < VDIM){ row_ptr[idx] = base + excl; cursor[idx] = base + excl; }
    base += buf[255];
    __syncthreads();
  }
  if (tid == 0) row_ptr[VDIM] = base;
}

__global__ void scatter_kernel(const int* __restrict__ ei, int* __restrict__ cursor,
                               int2* __restrict__ pk){
  int e = blockIdx.x * 256 + threadIdx.x;
  if (e < EDIM){
    int dst = ei[e*3], rel = ei[e*3+1], src = ei[e*3+2];
    if ((unsigned)dst < VDIM && (unsigned)rel < RDIM && (unsigned)src < VDIM){
      int p = atomicAdd(&cursor[dst], 1);
      pk[p] = make_int2(rel, src);
    }
  }
}

// ---- z projections ----
__global__ void zcalc_kernel(const float* __restrict__ z,
                             const float* __restrict__ qkzw, const float* __restrict__ qkzb,
                             const float* __restrict__ vfw,  const float* __restrict__ vfb,
                             float* __restrict__ qk_z, float* __restrict__ zr){
  int idx = blockIdx.x * 256 + threadIdx.x;
  if (idx >= 49152) return;
  int which = idx >> 14;
  int r = idx & 16383;
  int b = r >> 12;
  int j = r & 4095;
  const float* wrow; float bias; float* outp;
  if (which == 0){ wrow = qkzw + (size_t)j*DDIM; bias = qkzb[j]; outp = qk_z; }
  else { int i = which - 1; wrow = vfw + (size_t)(i*4096 + j)*DDIM; bias = vfb[i*4096 + j]; outp = zr + i*16384; }
  const float* zrow = z + (size_t)b*DDIM;
  float acc = bias;
  for (int d = 0; d < DDIM; d++) acc += zrow[d] * wrow[d];
  outp[r] = acc;
}

// ---- rspmm gather (CSR, packed idx) ----
template<typename T>
__global__ __launch_bounds__(256) void rspmm_gather(
    const int* __restrict__ row_ptr, const int2* __restrict__ pk,
    const float* __restrict__ zrel, const T* __restrict__ X, T* __restrict__ out){
  int v = blockIdx.x;
  int b = threadIdx.x >> 6, d = threadIdx.x & 63;
  int s = row_ptr[v], e = row_ptr[v+1];
  const float* zb = zrel + b*RDIM*DDIM + d;
  size_t xb = (size_t)b*VDIM*64 + d;
  float acc = 0.f;
  for (int i = s; i < e; i++){
    int2 ed = pk[i];
    acc += zb[ed.x*64] * ldf(X, xb + (size_t)ed.y*64);
  }
  stf(out, ((size_t)b*VDIM + v)*64 + d, acc);
}

// ---- init qk_x: fused MLP, weights in registers ----
template<typename T>
__global__ __launch_bounds__(256) void init_qk_kernel(
    const float* __restrict__ x, const float* __restrict__ noise,
    const float* __restrict__ w1, const float* __restrict__ b1,
    const float* __restrict__ w2, const float* __restrict__ b2,
    T* __restrict__ out){
  __shared__ __align__(16) float tb[4*64];
  __shared__ __align__(16) float hb[4*64];
  int tid = threadIdx.x, lane = tid & 63, wid = tid >> 6;
  float w1a[64]; float4 w2r[16];
  #pragma unroll
  for (int i = 0; i < 64; i++) w1a[i] = w1[lane*65 + i];
  float wn = w1[lane*65 + 64];
  const float4* w2v = (const float4*)w2;
  #pragma unroll
  for (int i = 0; i < 16; i++) w2r[i] = w2v[lane*16 + i];
  float b1l = b1[lane], b2l = b2[lane];
  const float4* tbv = (const float4*)tb;
  const float4* hbv = (const float4*)hb;
  for (int r0 = blockIdx.x*4; r0 < BV; r0 += gridDim.x*4){
    int row = r0 + wid;
    size_t rb = (size_t)row*64;
    tb[wid*64+lane] = x[rb+lane];
    float nz = noise[row];
    __syncthreads();
    float h = b1l + wn * nz;
    #pragma unroll
    for (int i4 = 0; i4 < 16; i4++){
      float4 t = tbv[wid*16 + i4];
      h += w1a[i4*4+0]*t.x + w1a[i4*4+1]*t.y + w1a[i4*4+2]*t.z + w1a[i4*4+3]*t.w;
    }
    hb[wid*64+lane] = fmaxf(h, 0.f);
    __syncthreads();
    float y = b2l;
    #pragma unroll
    for (int i4 = 0; i4 < 16; i4++) y += dot4(w2r[i4], hbv[wid*16 + i4]);
    stf(out, rb+lane, y);
  }
}

// ---- init v_x ----
template<typename T>
__global__ __launch_bounds__(256) void init_v_kernel(
    const float* __restrict__ x, const int* __restrict__ h_index,
    const float* __restrict__ w1, const float* __restrict__ b1,
    const float* __restrict__ w2, const float* __restrict__ b2,
    T* __restrict__ out){
  __shared__ __align__(16) float tb[4*64];
  __shared__ __align__(16) float hb[4*64];
  int tid = threadIdx.x, lane = tid & 63, wid = tid >> 6;
  float4 w1r[16], w2r[16];
  const float4* w1v = (const float4*)w1;     // [64][128] -> row stride 32 float4
  const float4* w2v = (const float4*)w2;
  #pragma unroll
  for (int i = 0; i < 16; i++){ w1r[i] = w1v[lane*32 + i]; w2r[i] = w2v[lane*16 + i]; }
  float rsv = 0.f;
  #pragma unroll
  for (int i = 0; i < 16; i++){ float4 t = w1v[lane*32 + 16 + i]; rsv += t.x+t.y+t.z+t.w; }
  float b1l = b1[lane], b2l = b2[lane];
  int h0 = h_index[0], h1 = h_index[1], h2 = h_index[2], h3 = h_index[3];
  const float4* tbv = (const float4*)tb;
  const float4* hbv = (const float4*)hb;
  for (int r0 = blockIdx.x*4; r0 < BV; r0 += gridDim.x*4){
    int row = r0 + wid;
    int b = row / VDIM, v = row - b*VDIM;
    int hv = (b == 0) ? h0 : (b == 1) ? h1 : (b == 2) ? h2 : h3;
    size_t rb = (size_t)row*64;
    tb[wid*64+lane] = x[rb+lane];
    __syncthreads();
    float h = b1l + ((v == hv) ? rsv : 0.f);
    #pragma unroll
    for (int i4 = 0; i4 < 16; i4++) h += dot4(w1r[i4], tbv[wid*16 + i4]);
    hb[wid*64+lane] = fmaxf(h, 0.f);
    __syncthreads();
    float y = b2l;
    #pragma unroll
    for (int i4 = 0; i4 < 16; i4++) y += dot4(w2r[i4], hbv[wid*16 + i4]);
    stf(out, rb+lane, y);
  }
}

// ---- loop body: X = LN(mlp2(O + alpha*X))*ng + nb + X ----
template<typename T>
__global__ __launch_bounds__(256) void loop_body_kernel(
    const T* __restrict__ O, T* __restrict__ X,
    const float* __restrict__ alpha, const float* __restrict__ w1, const float* __restrict__ b1,
    const float* __restrict__ w2, const float* __restrict__ b2,
    const float* __restrict__ ng, const float* __restrict__ nb){
  __shared__ __align__(16) float tb[4*64];
  __shared__ __align__(16) float hb[4*64];
  int tid = threadIdx.x, lane = tid & 63, wid = tid >> 6;
  float4 w1r[16], w2r[16];
  const float4* w1v = (const float4*)w1;
  const float4* w2v = (const float4*)w2;
  #pragma unroll
  for (int i = 0; i < 16; i++){ w1r[i] = w1v[lane*16 + i]; w2r[i] = w2v[lane*16 + i]; }
  float all = alpha[lane], b1l = b1[lane], b2l = b2[lane];
  float ngl = ng[lane], nbl = nb[lane];
  const float4* tbv = (const float4*)tb;
  const float4* hbv = (const float4*)hb;
  for (int r0 = blockIdx.x*4; r0 < BV; r0 += gridDim.x*4){
    int row = r0 + wid;
    size_t rb = (size_t)row*64;
    float xs = ldf(X, rb+lane);
    tb[wid*64+lane] = ldf(O, rb+lane) + all * xs;
    __syncthreads();
    float h = b1l;
    #pragma unroll
    for (int i4 = 0; i4 < 16; i4++) h += dot4(w1r[i4], tbv[wid*16 + i4]);
    hb[wid*64+lane] = fmaxf(h, 0.f);
    __syncthreads();
    float y = b2l;
    #pragma unroll
    for (int i4 = 0; i4 < 16; i4++) y += dot4(w2r[i4], hbv[wid*16 + i4]);
    float mu = wave_sum64(y) * (1.f/64.f);
    float c = y - mu;
    float var = wave_sum64(c*c) * (1.f/64.f);
    stf(X, rb+lane, c * rsqrtf(var + LN_EPS) * ngl + nbl + xs);
  }
}

// ---- qkproj: weights in regs, per-block partial reduction ----
template<typename T>
__global__ __launch_bounds__(256) void qkproj_kernel(
    T* __restrict__ Xqk, const T* __restrict__ Xv,
    const float* __restrict__ w, const float* __restrict__ bias,
    float* __restrict__ partial){
  __shared__ __align__(16) float tb[4*64];
  __shared__ __align__(16) float red[4*1152];
  int tid = threadIdx.x, lane = tid & 63, wid = tid >> 6;
  float4 wq[16], wk[16];
  const float4* wv = (const float4*)w;
  #pragma unroll
  for (int i = 0; i < 16; i++){ wq[i] = wv[lane*16 + i]; wk[i] = wv[(64+lane)*16 + i]; }
  float bq = bias[lane], bk = bias[64+lane];
  int b = blockIdx.x / NBB, blk = blockIdx.x % NBB;
  float kv[16];
  #pragma unroll
  for (int i = 0; i < 16; i++) kv[i] = 0.f;
  float ks = 0.f, vs = 0.f;
  const float4* tbv = (const float4*)tb;
  for (int v0 = blk*4; v0 < VDIM; v0 += NBB*4){
    int v = v0 + wid;
    size_t row = ((size_t)b*VDIM + v)*64;
    tb[wid*64+lane] = ldf(Xqk, row+lane);
    __syncthreads();
    float q = bq, k = bk;
    #pragma unroll
    for (int i4 = 0; i4 < 16; i4++){
      float4 t = tbv[wid*16 + i4];
      q += dot4(wq[i4], t);
      k += dot4(wk[i4], t);
    }
    float qn2 = head_sum16(q*q);
    float kn2 = head_sum16(k*k);
    q = q / fmaxf(sqrtf(qn2), 1e-12f);
    k = k / fmaxf(sqrtf(kn2), 1e-12f);
    float vv = ldf(Xv, row+lane);
    stf(Xqk, row+lane, q);             // qn in place
    ks += k; vs += vv;
    int base = lane & 48;              // h*16
    #pragma unroll
    for (int dl = 0; dl < 16; dl++){
      float vdl = __shfl(vv, base + dl, 64);
      kv[dl] += k * vdl;
    }
    __syncthreads();
  }
  // per-wave partials -> LDS -> block partial (coalesced)
  float* rw = red + wid*1152;
  #pragma unroll
  for (int dl = 0; dl < 16; dl++) rw[lane*16 + dl] = kv[dl];
  rw[1024 + lane] = ks;
  rw[1088 + lane] = vs;
  __syncthreads();
  float* P = partial + (size_t)blockIdx.x*1152;
  for (int j = tid; j < 1152; j += 256)
    P[j] = red[j] + red[1152+j] + red[2304+j] + red[3456+j];
}

// ---- reduce qkproj partials ----
__global__ void qkred_kernel(const float* __restrict__ partial,
                             float* __restrict__ kvs, float* __restrict__ ksum, float* __restrict__ vsum){
  int b = blockIdx.x / 5, ch = blockIdx.x % 5;
  int j = ch*256 + threadIdx.x;
  if (j >= 1152) return;
  const float* P = partial + (size_t)b*NBB*1152;
  float s = 0.f;
  for (int t = 0; t < NBB; t++) s += P[(size_t)t*1152 + j];
  if (j < 1024)      kvs[b*1024 + j] = s;
  else if (j < 1088) ksum[b*64 + (j-1024)] = s;
  else               vsum[b*64 + (j-1088)] = s;
}

// ---- attention finalize + LN ----
template<typename T>
__global__ __launch_bounds__(256) void attn_final_kernel(
    const float* __restrict__ x, T* __restrict__ A, const T* __restrict__ Xv,
    const float* __restrict__ kvs, const float* __restrict__ ksum, const float* __restrict__ vsum,
    const float* __restrict__ g, const float* __restrict__ bb){
  __shared__ float kvss[4096], kss[256], vss[256];
  int tid = threadIdx.x, lane = tid & 63, wid = tid >> 6;
  for (int i = tid; i < 4096; i += 256) kvss[i] = kvs[i];
  kss[tid] = ksum[tid];
  vss[tid] = vsum[tid];
  float gl = g[lane], bl = bb[lane];
  __syncthreads();
  int h16 = lane & 48, dl = lane & 15;
  for (int r0 = blockIdx.x*4; r0 < BV; r0 += gridDim.x*4){
    int row = r0 + wid;
    int b = row / VDIM;
    size_t rb = (size_t)row*64;
    float qv = ldf(A, rb+lane);
    float vv = ldf(Xv, rb+lane);
    float num = vss[b*64+lane] + vv * (float)VDIM;
    float den = 2.0f * (float)VDIM;
    int kbase = b*1024 + h16*16 + dl;
    int ksbase = b*64 + h16;
    #pragma unroll
    for (int j = 0; j < 16; j++){
      float qj = __shfl(qv, h16 + j, 64);
      num += qj * kvss[kbase + j*16];
      den += qj * kss[ksbase + j];
    }
    float y = x[rb+lane] + num / den;
    float mu = wave_sum64(y) * (1.f/64.f);
    float c = y - mu;
    float var = wave_sum64(c*c) * (1.f/64.f);
    stf(A, rb+lane, c * rsqrtf(var + LN_EPS) * gl + bl);
  }
}

// ---- final FFN + LN -> fp32 out ----
template<typename T>
__global__ __launch_bounds__(256) void final_kernel(
    const T* __restrict__ X1,
    const float* __restrict__ w1, const float* __restrict__ b1,
    const float* __restrict__ w2, const float* __restrict__ b2,
    const float* __restrict__ g, const float* __restrict__ bb,
    float* __restrict__ out){
  __shared__ __align__(16) float tb[4*64];
  __shared__ __align__(16) float hb[4*64];
  int tid = threadIdx.x, lane = tid & 63, wid = tid >> 6;
  float4 w1r[16], w2r[16];
  const float4* w1v = (const float4*)w1;
  const float4* w2v = (const float4*)w2;
  #pragma unroll
  for (int i = 0; i < 16; i++){ w1r[i] = w1v[lane*16 + i]; w2r[i] = w2v[lane*16 + i]; }
  float b1l = b1[lane], b2l = b2[lane], gl = g[lane], bl = bb[lane];
  const float4* tbv = (const float4*)tb;
  const float4* hbv = (const float4*)hb;
  for (int r0 = blockIdx.x*4; r0 < BV; r0 += gridDim.x*4){
    int row = r0 + wid;
    size_t rb = (size_t)row*64;
    float xv = ldf(X1, rb+lane);
    tb[wid*64+lane] = xv;
    __syncthreads();
    float h = b1l;
    #pragma unroll
    for (int i4 = 0; i4 < 16; i4++) h += dot4(w1r[i4], tbv[wid*16 + i4]);
    hb[wid*64+lane] = fmaxf(h, 0.f);
    __syncthreads();
    float y = b2l;
    #pragma unroll
    for (int i4 = 0; i4 < 16; i4++) y += dot4(w2r[i4], hbv[wid*16 + i4]);
    float t = xv + y;
    float mu = wave_sum64(t) * (1.f/64.f);
    float c = t - mu;
    float var = wave_sum64(c*c) * (1.f/64.f);
    out[rb+lane] = c * rsqrtf(var + LN_EPS) * gl + bl;
  }
}

// ================= host side =================
static const int DICT_SIZES[42] = {
  5120000,256,256,80000,262144,4096,4160,64,4096,64,
  8192,64,4096,64,8192,128,8192,128,8192,128,
  128,128,128,524288,8192,8192,128,8192,128,128,
  128,128,4096,64,4096,64,64,64,64,64,
  4,600000};

template<typename T>
static void run_pipeline(const float* const* N, const int* hi,
                         const int* row_ptr, const int2* pk,
                         float* qk_z, float* zr, float* kvs, float* part,
                         T* Obuf, T* A, T* B, float* outp, hipStream_t stream){
  float* ksum = kvs + 4096;
  float* vsum = kvs + 4352;
  const int GM = 2000;

  zcalc_kernel<<<192, 256, 0, stream>>>(N[1], N[4], N[5], N[23], N[24], qk_z, zr);

  init_qk_kernel<T><<<GM, 256, 0, stream>>>(N[0], N[3], N[6], N[7], N[8], N[9], A);
  for (int i = 0; i < 2; i++){
    rspmm_gather<T><<<VDIM, 256, 0, stream>>>(row_ptr, pk, qk_z, A, Obuf);
    loop_body_kernel<T><<<GM, 256, 0, stream>>>(Obuf, A, N[20] + i*64, N[16] + i*4096, N[17] + i*64,
                                                N[18] + i*4096, N[19] + i*64, N[21] + i*64, N[22] + i*64);
  }
  init_v_kernel<T><<<GM, 256, 0, stream>>>(N[0], hi, N[10], N[11], N[12], N[13], B);
  for (int i = 0; i < 2; i++){
    rspmm_gather<T><<<VDIM, 256, 0, stream>>>(row_ptr, pk, zr + i*16384, B, Obuf);
    loop_body_kernel<T><<<GM, 256, 0, stream>>>(Obuf, B, N[29] + i*64, N[25] + i*4096, N[26] + i*64,
                                                N[27] + i*4096, N[28] + i*64, N[30] + i*64, N[31] + i*64);
  }
  qkproj_kernel<T><<<BDIM*NBB, 256, 0, stream>>>(A, B, N[14], N[15], part);
  qkred_kernel<<<20, 256, 0, stream>>>(part, kvs, ksum, vsum);
  attn_final_kernel<T><<<GM, 256, 0, stream>>>(N[0], A, B, kvs, ksum, vsum, N[36], N[37]);
  final_kernel<T><<<GM, 256, 0, stream>>>(A, N[32], N[33], N[34], N[35], N[38], N[39], outp);
}

extern "C" void kernel_launch(void* const* d_in, const int* in_sizes, int n_in,
                              void* d_out, int out_size, void* d_ws, size_t ws_size,
                              hipStream_t stream){
  float* outp = (float*)d_out;
  const int GOUT = (out_size + 255) / 256;

  if (n_in != 42){
    fill_kernel<<<GOUT, 256, 0, stream>>>(outp, 2000.0f + (float)n_in, out_size);
    return;
  }
  auto sz_ok = [&](int s, int e)->bool{
    if (s == e) return true;
    if ((e == 4 || e == 600000) && s == 2*e) return true;
    return false;
  };
  int bad = -1;
  for (int i = 0; i < 42 && bad < 0; i++)
    if (!sz_ok(in_sizes[i], DICT_SIZES[i])) bad = i;
  if (bad >= 0){
    fill_kernel<<<GOUT, 256, 0, stream>>>(outp, 1000.0f + (float)bad, out_size);
    return;
  }

  const float* N[40];
  for (int i = 0; i < 40; i++) N[i] = (const float*)d_in[i];
  const int* hi_raw = (const int*)d_in[40];
  const int* ei_raw = (const int*)d_in[41];

  char* p = (char*)d_ws;
  auto alloc = [&](size_t bytes)->char*{ char* r = p; p += (bytes + 255) / 256 * 256; return r; };
  int* ei      = (int*)alloc((size_t)3*EDIM*4);
  int* hi      = (int*)alloc(256);
  int* counts  = (int*)alloc((VDIM+1)*4);
  int* row_ptr = (int*)alloc((VDIM+1)*4);
  int* cursor  = (int*)alloc((VDIM+1)*4);
  int2* pk     = (int2*)alloc((size_t)EDIM*8);
  float* qk_z  = (float*)alloc(16384u*4);
  float* zr    = (float*)alloc(32768u*4);
  float* kvs   = (float*)alloc(4608u*4);
  float* part  = (float*)alloc((size_t)BDIM*NBB*1152*4);
  size_t fixed = (size_t)(p - (char*)d_ws);
  bool f32ok = ws_size >= fixed + 3*(size_t)BV*64*4 + 1024;

  prep_idx_kernel<<<(3*EDIM+255)/256, 256, 0, stream>>>(ei_raw, hi_raw, ei, hi);
  zero_kernel<<<(VDIM+256)/256, 256, 0, stream>>>(counts);
  count_kernel<<<(EDIM+255)/256, 256, 0, stream>>>(ei, counts);
  scan_kernel<<<1, 256, 0, stream>>>(counts, row_ptr, cursor);
  scatter_kernel<<<(EDIM+255)/256, 256, 0, stream>>>(ei, cursor, pk);

  if (f32ok){
    float* Obuf = (float*)alloc((size_t)BV*64*4);
    float* A    = (float*)alloc((size_t)BV*64*4);
    float* B    = (float*)alloc((size_t)BV*64*4);
    run_pipeline<float>(N, hi, row_ptr, pk, qk_z, zr, kvs, part, Obuf, A, B, outp, stream);
  } else {
    bf16* Obuf = (bf16*)alloc((size_t)BV*64*2);
    bf16* A    = (bf16*)alloc((size_t)BV*64*2);
    bf16* B    = (bf16*)alloc((size_t)BV*64*2);
    run_pipeline<bf16>(N, hi, row_ptr, pk, qk_z, zr, kvs, part, Obuf, A, B, outp, stream);
  }
}